// Round 7
// baseline (1293.564 us; speedup 1.0000x reference)
//
#include <hip/hip_runtime.h>

// TitansMemory: per-row delta-rule-with-momentum scan. B=16, L=8192, DK=DV=128.
//   s = C_S*(w·k - v) ; m̂ = β m̂ + s k ; w = (1-α) w + m̂ ; y = w·q
// Mapping: TWO rows per wave (lanes 0-31 row0, 32-63 row1), 4 cols/lane (f4),
// 1024 single-wave blocks = 1 wave/SIMD. Pinned asm loads (r3-verified),
// 2-buffer A/B pipeline with WAITP-at-window-start (r4-verified queue math,
// max 52 outstanding VMEM).
// Round 7 = IN-CHUNK Gram lookahead (bisection of r5/r6 which aborted):
//  - NO cross-chunk reads: at window start the state is w_{t-1} for the
//    chunk's first step, so s_0 = C_S*(dot(w,k0) - v0) directly, and
//    base_1 = CA*dot(w,k1) + CB*dot(m,k1) + CV*v1. Steps 0..5 produce bases
//    for steps 2..7 off-chain via dot(w_{t-2},k_t)/dot(m_{t-2},k_t)
//    projections; steps 6,7 produce none.
//  - NO 3rd buffer: ~190 VGPRs (r5/r6's ~280 exceeded the 256 arch-VGPR
//    ceiling -> prime crash suspect with pinned-asm quad outputs).
// Serial chain per step: ONE scalar fma (s_t = fma(s_{t-1}, gs_t, base_t));
// one exposed head-reduce per 8 steps. All reductions use the r4-verified
// dual-input permlane16_swap pair-reduce.

#define L_ 8192
#define D_ 128

typedef __attribute__((ext_vector_type(4))) float f4;
typedef __attribute__((ext_vector_type(2))) float f2;
typedef __attribute__((ext_vector_type(2))) unsigned int u2;

constexpr float A_    = 0.98f;
constexpr float BETA_ = 0.9f;
constexpr float C_S   = -0.02f;       // -2*lr*(1-beta)
constexpr float CA_   = C_S * A_;     // base coef for Pw
constexpr float CB_   = C_S * BETA_;  // base coef for Pm
constexpr float CV_   = -C_S;         // base coef for v

template <int CTRL>
__device__ __forceinline__ float dpp_add(float x) {
  int y = __builtin_amdgcn_update_dpp(0, __float_as_int(x), CTRL, 0xF, 0xF, true);
  return x + __int_as_float(y);
}

__device__ __forceinline__ float fold4(f4 d) {
  f2 t = {d.x + d.z, d.y + d.w};
  return t.x + t.y;
}

__device__ __forceinline__ u2 swap16(float a, float b) {
  return __builtin_amdgcn_permlane16_swap(__float_as_uint(a), __float_as_uint(b),
                                          false, false);
}

// Dual 32-lane reduce: {sum32(a), sum32(b)} valid in EVERY lane of each half.
// 6 cross-lane ops for 2 reductions. (Semantics harness-verified r1/r2/r4.)
__device__ __forceinline__ f2 reduce2(float a, float b) {
  u2 r = swap16(a, b);
  float c = __uint_as_float(r.x) + __uint_as_float(r.y);
  c = dpp_add<0x121>(c);
  c = dpp_add<0x122>(c);
  c = dpp_add<0x124>(c);
  c = dpp_add<0x128>(c);
  u2 u = swap16(c, c);          // u.x = even-16-group (a) sum bcast,
  return {__uint_as_float(u.x), // u.y = odd-16-group (b) sum bcast
          __uint_as_float(u.y)};
}

// Pinned loads: asm volatile keeps issue placement and register residency.
#define GLD4(dst, addr, OFF) \
  asm volatile("global_load_dwordx4 %0, %1, off offset:" OFF : "=v"(dst) : "v"(addr))
#define GLD1(dst, addr, OFF) \
  asm volatile("global_load_dword %0, %1, off offset:" OFF : "=v"(dst) : "v"(addr))

#define ISSUE_CHUNK(kb, qb, vb)                            \
  do {                                                     \
    GLD4(kb[0], ka64, "0");    GLD4(qb[0], qa64, "0");    GLD1(vb[0], va64, "0");    \
    GLD4(kb[1], ka64, "512");  GLD4(qb[1], qa64, "512");  GLD1(vb[1], va64, "512");  \
    GLD4(kb[2], ka64, "1024"); GLD4(qb[2], qa64, "1024"); GLD1(vb[2], va64, "1024"); \
    GLD4(kb[3], ka64, "1536"); GLD4(qb[3], qa64, "1536"); GLD1(vb[3], va64, "1536"); \
    GLD4(kb[4], ka64, "2048"); GLD4(qb[4], qa64, "2048"); GLD1(vb[4], va64, "2048"); \
    GLD4(kb[5], ka64, "2560"); GLD4(qb[5], qa64, "2560"); GLD1(vb[5], va64, "2560"); \
    GLD4(kb[6], ka64, "3072"); GLD4(qb[6], qa64, "3072"); GLD1(vb[6], va64, "3072"); \
    GLD4(kb[7], ka64, "3584"); GLD4(qb[7], qa64, "3584"); GLD1(vb[7], va64, "3584"); \
    uint64_t bump_ = (sc < 1023) ? 4096u : 0u;             \
    ka64 += bump_; qa64 += bump_; va64 += bump_; ++sc;     \
  } while (0)

#define WAITP                                              \
  do {                                                     \
    asm volatile("s_waitcnt vmcnt(24)");                   \
    __builtin_amdgcn_sched_barrier(0);                     \
  } while (0)

__global__ __launch_bounds__(64, 1)
void TitansMemory_188978561365_kernel(const float* __restrict__ Q,
                                      const float* __restrict__ K,
                                      const float* __restrict__ V,
                                      float* __restrict__ Y) {
  const int lane  = threadIdx.x;              // 0..63
  const int wid   = blockIdx.x;               // 0..1023
  const int batch = wid >> 6;                 // 64 waves per batch (128 rows)
  const int col   = (lane & 31) << 2;         // 4 k-cols per lane

  const size_t bbase = (size_t)batch * (size_t)L_ * D_;
  uint64_t ka64 = (uint64_t)(K + bbase + col);
  uint64_t qa64 = (uint64_t)(Q + bbase + col);
  uint64_t va64 = (uint64_t)(V + bbase + ((wid & 63) << 1) + (lane >> 5));
  // y store base (r4-verified): 16-group g holds (row=g>>1, t-parity=g&1);
  // lanes 0,16,32,48 store.
  float* yb = Y + bbase + ((wid & 63) << 1) + (lane >> 5)
                + (size_t)((lane >> 4) & 1) * D_;
  int sc = 0;  // chunks issued (tail clamp)

  const f4 av = {A_, A_, A_, A_};
  const f4 bv = {BETA_, BETA_, BETA_, BETA_};

  f4 w = {0.f, 0.f, 0.f, 0.f}, m = {0.f, 0.f, 0.f, 0.f};
  float ey[8];

  f4 kA[8], qA[8]; float vA[8];
  f4 kB[8], qB[8]; float vB[8];

  // Apply one step given its (already final) s: update m,w; stash y partial.
  auto apply = [&](float s, const f4& kj, const f4& qj, float& eyj) {
    f4 s4 = {s, s, s, s};
    m = __builtin_elementwise_fma(s4, kj, bv * m);
    w = __builtin_elementwise_fma(av, w, m);
    eyj = fold4(w * qj);                  // exact y partial, reduce deferred
  };

  // Base for step t=j+2 from state after step j (= w_{t-2}, m_{t-2}).
  auto mkbase = [&](const f4& kp2, float vp2) -> float {
    f2 P = reduce2(fold4(w * kp2), fold4(m * kp2));
    return fmaf(CA_, P.x, fmaf(CB_, P.y, CV_ * vp2));
  };

  auto window = [&](f4 (&kX)[8], f4 (&qX)[8], float (&vX)[8]) {
    // ---- head: direct s_0, base_1, and the k-Gram burst (all off-chain,
    // mutually independent reduces) ----
    f2 h0  = reduce2(fold4(w * kX[0]), fold4(w * kX[1]));    // D0w, D1w
    f2 h1  = reduce2(fold4(m * kX[1]), fold4(kX[0] * kX[1]));// D1m, g1
    f2 g23 = reduce2(fold4(kX[1] * kX[2]), fold4(kX[2] * kX[3]));
    f2 g45 = reduce2(fold4(kX[3] * kX[4]), fold4(kX[4] * kX[5]));
    f2 g67 = reduce2(fold4(kX[5] * kX[6]), fold4(kX[6] * kX[7]));

    float s = fmaf(C_S, h0.x, CV_ * vX[0]);                  // s_0 (direct)
    apply(s, kX[0], qX[0], ey[0]);
    float b2 = mkbase(kX[2], vX[2]);
    float base1 = fmaf(CA_, h0.y, fmaf(CB_, h1.x, CV_ * vX[1]));
    s = fmaf(s, C_S * h1.y, base1);                          // s_1
    apply(s, kX[1], qX[1], ey[1]);
    float b3 = mkbase(kX[3], vX[3]);
    s = fmaf(s, C_S * g23.x, b2);                            // s_2
    apply(s, kX[2], qX[2], ey[2]);
    float b4 = mkbase(kX[4], vX[4]);
    s = fmaf(s, C_S * g23.y, b3);                            // s_3
    apply(s, kX[3], qX[3], ey[3]);
    float b5 = mkbase(kX[5], vX[5]);
    s = fmaf(s, C_S * g45.x, b4);                            // s_4
    apply(s, kX[4], qX[4], ey[4]);
    float b6 = mkbase(kX[6], vX[6]);
    s = fmaf(s, C_S * g45.y, b5);                            // s_5
    apply(s, kX[5], qX[5], ey[5]);
    float b7 = mkbase(kX[7], vX[7]);
    s = fmaf(s, C_S * g67.x, b6);                            // s_6
    apply(s, kX[6], qX[6], ey[6]);
    s = fmaf(s, C_S * g67.y, b7);                            // s_7
    apply(s, kX[7], qX[7], ey[7]);

    // ---- deferred y: 4 pair-reduces + predicated stores (r4-verified) ----
#pragma unroll
    for (int p = 0; p < 4; ++p) {
      u2 r = swap16(ey[2 * p], ey[2 * p + 1]);
      float c = __uint_as_float(r.x) + __uint_as_float(r.y);
      c = dpp_add<0x121>(c);
      c = dpp_add<0x122>(c);
      c = dpp_add<0x124>(c);
      c = dpp_add<0x128>(c);
      if ((lane & 15) == 0) yb[(size_t)(2 * p) * D_] = c;
    }
    yb += 8 * D_;
    ISSUE_CHUNK(kX, qX, vX);   // refill this buffer (chunk c+2)
  };

  // Prologue: two chunks in flight (48 loads; max outstanding anywhere = 52).
  ISSUE_CHUNK(kA, qA, vA);
  ISSUE_CHUNK(kB, qB, vB);

  for (int it = 0; it < 512; ++it) {   // 1024 windows of 8 steps
    WAITP;                             // A-chunk resident
    window(kA, qA, vA);
    WAITP;                             // B-chunk resident
    window(kB, qB, vB);
  }
}

extern "C" void kernel_launch(void* const* d_in, const int* in_sizes, int n_in,
                              void* d_out, int out_size, void* d_ws, size_t ws_size,
                              hipStream_t stream) {
  const float* Q = (const float*)d_in[0];
  const float* K = (const float*)d_in[1];
  const float* V = (const float*)d_in[2];
  float* Y = (float*)d_out;
  dim3 grid(1024), block(64);
  hipLaunchKernelGGL(TitansMemory_188978561365_kernel, grid, block, 0, stream,
                     Q, K, V, Y);
}